// Round 10
// baseline (49.883 us; speedup 1.0000x reference)
//
#include <hip/hip_runtime.h>
#include <math.h>

#define B_ 4
#define N_ 33600
#define G_ 100
#define NCLS 80
#define STRIDE 85   // 4 box + 80 cls + 1 obj
#define TK 10
#define K1BLK 132   // ceil(N_/256)
#define K2TOT (B_ * G_)
#define CAP 2048    // LDS candidate capacity per pass (E[cnt]~160)
#define PADW (K1BLK * 256)

__device__ __forceinline__ float sigmoidf_(float x) {
    return 1.0f / (1.0f + expf(-x));
}
__device__ __forceinline__ float softplusf_(float x) {
    return fmaxf(x, 0.0f) + log1pf(expf(-fabsf(x)));
}
__device__ __forceinline__ float waveRedSum(float v) {
    #pragma unroll
    for (int off = 32; off; off >>= 1) v += __shfl_xor(v, off, 64);
    return v;
}

// ---------------------------------------------------------------- K1
// mask -> in-block ordered scatter into padded cidx + bcount; bkey init;
// obj softplus partials; ballot-cooperative spsum[n]; accumulator zeroing.
__global__ void k1_prep(const float* __restrict__ gtb,
                        const float* __restrict__ anc,
                        const float* __restrict__ pred,
                        int* __restrict__ cidx_pad,    // [B_][PADW]
                        float* __restrict__ spsum,     // indexed by anchor n
                        unsigned long long* __restrict__ bkey,
                        float* __restrict__ pobj,      // [B_*K1BLK]
                        int* __restrict__ bcount,      // [B_*K1BLK]
                        float* __restrict__ acc,       // [4] telescoped sums
                        unsigned int* __restrict__ done)
{
    __shared__ float gcx[G_], gcy[G_];
    __shared__ int wsum[4];
    __shared__ float wsf[4];
    const int b = blockIdx.y;
    const int tid = threadIdx.x;
    const int lane = tid & 63, wid = tid >> 6;
    if (blockIdx.x == 0 && b == 0 && tid == 0) {
        *done = 0u;                               // finisher ticket
        acc[0] = 0.0f; acc[1] = 0.0f; acc[2] = 0.0f; acc[3] = 0.0f;
    }
    if (tid < G_) {
        gcx[tid] = gtb[(b * G_ + tid) * 4 + 0];
        gcy[tid] = gtb[(b * G_ + tid) * 4 + 1];
    }
    __syncthreads();
    const int n = blockIdx.x * blockDim.x + tid;
    float so = 0.0f;
    int c = 0;
    if (n < N_) {
        const size_t a_ = (size_t)b * N_ + n;
        bkey[a_] = 0xFFFFFFFFFFFFFFFFull;
        so = softplusf_(pred[a_ * STRIDE + (STRIDE - 1)]);
        const float2 a = ((const float2*)anc)[n];
        #pragma unroll 10
        for (int g = 0; g < G_; ++g) {
            const float dx = a.x - gcx[g], dy = a.y - gcy[g];
            c |= (dx * dx + dy * dy < 6.25f) ? 1 : 0;
        }
        // cooperative spsum for each candidate lane in this wave
        unsigned long long m = __ballot(c != 0);
        while (m) {
            const int src = (int)__ffsll(m) - 1;
            m &= (m - 1);
            const int an = __shfl(n, src, 64);
            const float* row = pred + ((size_t)b * N_ + an) * STRIDE + 4;
            float s = softplusf_(sigmoidf_(row[lane]));
            if (lane < NCLS - 64) s += softplusf_(sigmoidf_(row[64 + lane]));
            s = waveRedSum(s);
            if (lane == 0) spsum[(size_t)b * N_ + an] = s;
        }
    }
    // in-block ordered scan -> padded scatter
    int incl = c;
    #pragma unroll
    for (int off = 1; off < 64; off <<= 1) {
        const int t = __shfl_up(incl, off, 64);
        if (lane >= off) incl += t;
    }
    if (lane == 63) wsum[wid] = incl;
    const float sow = waveRedSum(so);
    if (lane == 0) wsf[wid] = sow;
    __syncthreads();
    int wbase = 0;
    for (int w = 0; w < wid; ++w) wbase += wsum[w];
    if (c) cidx_pad[(size_t)b * PADW + blockIdx.x * 256 + wbase + incl - 1] = n;
    if (tid == 0) {
        pobj[b * K1BLK + blockIdx.x] = wsf[0] + wsf[1] + wsf[2] + wsf[3];
        bcount[b * K1BLK + blockIdx.x] = wsum[0] + wsum[1] + wsum[2] + wsum[3];
    }
}

// ---------------------------------------------------------------- contrib
// fg contribution of (anchor n, gt gg): per-lane focal cls share; lane 0
// carries box CIoU and obj logit. __noinline__ guarantees ONE code path so
// add- and subtract-events for the same (n,gg) are bit-identical.
struct Contrib { float cls, box, po; };
__device__ __noinline__ Contrib contribEval(const float* __restrict__ pred,
                                            const float* __restrict__ gtb,
                                            const int* __restrict__ gtc,
                                            int b, int n, int gg, int lane)
{
    Contrib c;
    const float* pr = pred + (size_t)(b * N_ + n) * STRIDE;
    const int cg_ = gtc[b * G_ + gg];
    float cl;
    {
        const float x = pr[4 + lane];
        const float t = (lane == cg_) ? 1.0f : 0.0f;
        const float bce = softplusf_(x) - x * t;
        const float p = sigmoidf_(x);
        const float pt = t * p + (1.0f - t) * (1.0f - p);
        const float om = 1.0f - pt;
        cl = 0.25f * om * om * bce;
    }
    if (lane < NCLS - 64) {
        const float x = pr[4 + 64 + lane];
        const float t = ((64 + lane) == cg_) ? 1.0f : 0.0f;
        const float bce = softplusf_(x) - x * t;
        const float p = sigmoidf_(x);
        const float pt = t * p + (1.0f - t) * (1.0f - p);
        const float om = 1.0f - pt;
        cl += 0.25f * om * om * bce;
    }
    c.cls = cl;
    c.box = 0.0f;
    c.po = 0.0f;
    if (lane == 0) {
        c.po = pr[STRIDE - 1];
        const float* gb = gtb + (b * G_ + gg) * 4;
        const float px = pr[0], py = pr[1], pw = pr[2], ph = pr[3];
        const float gx = gb[0], gy = gb[1], gw = gb[2], gh = gb[3];
        const float x11 = px - pw * 0.5f, y11 = py - ph * 0.5f;
        const float x12 = px + pw * 0.5f, y12 = py + ph * 0.5f;
        const float x21 = gx - gw * 0.5f, y21 = gy - gh * 0.5f;
        const float x22 = gx + gw * 0.5f, y22 = gy + gh * 0.5f;
        const float iw = fmaxf(fminf(x12, x22) - fmaxf(x11, x21), 0.0f);
        const float ih = fmaxf(fminf(y12, y22) - fmaxf(y11, y21), 0.0f);
        const float inter = iw * ih;
        const float uni = pw * ph + gw * gh - inter + 1e-7f;
        const float iou = inter / uni;
        const float cw = fmaxf(x12, x22) - fminf(x11, x21);
        const float chh = fmaxf(y12, y22) - fminf(y11, y21);
        const float c2 = cw * cw + chh * chh + 1e-7f;
        const float ddx = x11 + x12 - x21 - x22;
        const float ddy = y11 + y12 - y21 - y22;
        const float rho2 = (ddx * ddx + ddy * ddy) * 0.25f;
        const float dv = atanf(gw / (gh + 1e-7f)) - atanf(pw / (ph + 1e-7f));
        const float v = (float)(4.0 / (M_PI * M_PI)) * dv * dv;
        const float alpha = v / (v - iou + 1.0f + 1e-7f);
        const float ciou = iou - (rho2 / c2 + v * alpha);
        c.box = 1.0f - ciou;
    }
    return c;
}

// ---------------------------------------------------------------- K2
// one 256-thread block per (b,g): candidate assembly + 4-wave cost eval +
// top-10 merge + dyn_k; then TELESCOPING assignment: per keep, atomicMin
// installs (cost,g); on win add own contrib and subtract evicted gt's
// contrib -> accumulators telescope to the deduped fg loss. Ticket: the
// 400th block to finish reduces pobj + accumulators -> out.
__global__ void __launch_bounds__(256)
k2_assign(const float* __restrict__ pred,
          const float* __restrict__ gtb,
          const int* __restrict__ gtc,
          const int* __restrict__ cidx_pad,
          const int* __restrict__ bcount,
          const float* __restrict__ spsum,
          unsigned long long* __restrict__ bkey,
          const float* __restrict__ pobj,
          float* __restrict__ acc,
          unsigned int* __restrict__ done,
          float* __restrict__ out)
{
    const int b = blockIdx.y, g = blockIdx.x;
    const int tid = threadIdx.x;
    const int lane = tid & 63, wid = tid >> 6;

    __shared__ int scan[256];
    __shared__ int clds[CAP];
    __shared__ unsigned long long warr[4][TK];
    __shared__ float iolds[4];
    __shared__ unsigned long long swin[TK];
    __shared__ int sdk;

    const int myc = (tid < K1BLK) ? bcount[b * K1BLK + tid] : 0;
    scan[tid] = myc;
    __syncthreads();
    #pragma unroll
    for (int off = 1; off < 256; off <<= 1) {
        const int v = (tid >= off) ? scan[tid - off] : 0;
        __syncthreads();
        scan[tid] += v;
        __syncthreads();
    }
    const int cnt = scan[K1BLK - 1];
    const int allc = (cnt == 0) ? 1 : 0;   // fallback: all anchors candidates
    const int count = allc ? N_ : cnt;
    const int ebase = (tid == 0) ? 0 : scan[tid - 1];

    const float* gb = gtb + (b * G_ + g) * 4;
    const float gxc = gb[0], gyc = gb[1], gw = gb[2], gh = gb[3];
    const float gx1 = gxc - gw * 0.5f, gy1 = gyc - gh * 0.5f;
    const float gx2 = gxc + gw * 0.5f, gy2 = gyc + gh * 0.5f;
    const float garea = gw * gh;
    const int cls = gtc[b * G_ + g];

    float kcost[TK];
    int   kid[TK];
    #pragma unroll
    for (int j = 0; j < TK; ++j) { kcost[j] = INFINITY; kid[j] = 0x7FFFFFFF; }
    float iousum = 0.0f;

    for (int lo = 0; lo < count; lo += CAP) {
        const int hi = (count < lo + CAP) ? count : (lo + CAP);
        if (!allc && tid < K1BLK && myc) {
            for (int j = 0; j < myc; ++j) {
                const int d = ebase + j;
                if (d >= lo && d < hi)
                    clds[d - lo] = cidx_pad[(size_t)b * PADW + tid * 256 + j];
            }
        }
        __syncthreads();
        for (int i = lo + tid; i < hi; i += 256) {
            int n;
            float sp;
            if (allc) { // never taken in practice
                n = i;
                const float* pr0 = pred + (size_t)(b * N_ + n) * STRIDE;
                float s = 0.0f;
                for (int cc = 0; cc < NCLS; ++cc) s += softplusf_(sigmoidf_(pr0[4 + cc]));
                sp = s;
            } else {
                n = clds[i - lo];
                sp = spsum[(size_t)b * N_ + n];
            }
            const float* pr = pred + (size_t)(b * N_ + n) * STRIDE;
            const float px = pr[0], py = pr[1], pw = pr[2], ph = pr[3];
            const float x1 = px - pw * 0.5f, y1 = py - ph * 0.5f;
            const float x2 = px + pw * 0.5f, y2 = py + ph * 0.5f;
            const float iw = fmaxf(fminf(x2, gx2) - fmaxf(x1, gx1), 0.0f);
            const float ih = fmaxf(fminf(y2, gy2) - fmaxf(y1, gy1), 0.0f);
            const float inter = iw * ih;
            const float uni = pw * ph + garea - inter + 1e-7f;
            const float iou = inter / uni;
            iousum += iou;
            const float sgc = sigmoidf_(pr[4 + cls]);
            float c = -logf(iou + 1e-8f) + 3.0f * (sp - sgc);
            int   s = n;  // anchor id; ascending within a thread across iters
            #pragma unroll
            for (int j = 0; j < TK; ++j) {
                const bool lt = (c < kcost[j]);
                const float tc = kcost[j]; const int ts = kid[j];
                if (lt) { kcost[j] = c; kid[j] = s; c = tc; s = ts; }
            }
        }
        __syncthreads();
    }

    // per-wave iou sum -> LDS
    const float ios = waveRedSum(iousum);
    if (lane == 0) iolds[wid] = ios;

    // per-wave 10-round extract-min (keys (cost_bits<<32)|n; cost>0 always
    // so float bits are order-preserving; n unique -> keys unique)
    #pragma unroll
    for (int r = 0; r < TK; ++r) {
        const unsigned long long mykey =
            ((unsigned long long)__float_as_uint(kcost[0]) << 32) | (unsigned)kid[0];
        unsigned long long k2 = mykey;
        #pragma unroll
        for (int off = 32; off; off >>= 1) {
            const unsigned long long o = __shfl_xor(k2, off, 64);
            k2 = (o < k2) ? o : k2;
        }
        if (lane == 0) warr[wid][r] = k2;
        if (mykey == k2) {
            #pragma unroll
            for (int j = 0; j < TK - 1; ++j) { kcost[j] = kcost[j + 1]; kid[j] = kid[j + 1]; }
            kcost[TK - 1] = INFINITY; kid[TK - 1] = 0x7FFFFFFF;
        }
    }
    __syncthreads();

    // wave 0: merge 4x10 -> final 10 + dk -> LDS
    if (wid == 0) {
        unsigned long long key = 0xFFFFFFFFFFFFFFFFull;
        if (lane < 4 * TK) key = warr[lane / TK][lane % TK];
        #pragma unroll
        for (int r = 0; r < TK; ++r) {
            unsigned long long k2 = key;
            #pragma unroll
            for (int off = 32; off; off >>= 1) {
                const unsigned long long o = __shfl_xor(k2, off, 64);
                k2 = (o < k2) ? o : k2;
            }
            if (lane == 0) swin[r] = k2;
            if (key == k2) key = 0xFFFFFFFFFFFFFFFFull;
        }
        if (lane == 0) {
            const float total_iou = iolds[0] + iolds[1] + iolds[2] + iolds[3];
            const int kmax = (count < TK) ? count : TK;
            int dk = (int)floorf(total_iou);
            if (dk < 1) dk = 1;
            if (dk > kmax) dk = kmax;
            sdk = dk;
        }
    }
    __syncthreads();

    // telescoping assignment: keeps r distributed over the 4 waves
    float clsacc = 0.0f, box = 0.0f, posum = 0.0f, npos = 0.0f;
    const int dk = sdk;
    for (int r = wid; r < dk; r += 4) {
        const unsigned long long w = swin[r];
        const int n = (int)(unsigned)(w & 0xFFFFFFFFull);
        const unsigned long long mykey =
            (w & 0xFFFFFFFF00000000ull) | (unsigned)g;
        unsigned long long old = 0;
        if (lane == 0) old = atomicMin(&bkey[(size_t)b * N_ + n], mykey);
        old = __shfl(old, 0, 64);
        if (mykey < old) {
            const Contrib ca = contribEval(pred, gtb, gtc, b, n, g, lane);
            clsacc += ca.cls; box += ca.box; posum += ca.po;
            if (lane == 0) npos += 1.0f;
            if (old != 0xFFFFFFFFFFFFFFFFull) {
                const int og = (int)(unsigned)(old & 0xFFFFFFFFull);
                const Contrib cs = contribEval(pred, gtb, gtc, b, n, og, lane);
                clsacc -= cs.cls; box -= cs.box; posum -= cs.po;
                if (lane == 0) npos -= 1.0f;
            }
        }
    }

    posum = waveRedSum(posum);
    box = waveRedSum(box);
    clsacc = waveRedSum(clsacc);
    npos = waveRedSum(npos);
    __shared__ float ws4[4][4];
    if (lane == 0) {
        ws4[wid][0] = posum; ws4[wid][1] = box;
        ws4[wid][2] = clsacc; ws4[wid][3] = npos;
    }
    __syncthreads();
    __shared__ int amlast;
    if (tid == 0) {
        const float r0 = ws4[0][0] + ws4[1][0] + ws4[2][0] + ws4[3][0];
        const float r1 = ws4[0][1] + ws4[1][1] + ws4[2][1] + ws4[3][1];
        const float r2 = ws4[0][2] + ws4[1][2] + ws4[2][2] + ws4[3][2];
        const float r3 = ws4[0][3] + ws4[1][3] + ws4[2][3] + ws4[3][3];
        atomicAdd(&acc[0], r0);
        atomicAdd(&acc[1], r1);
        atomicAdd(&acc[2], r2);
        atomicAdd(&acc[3], r3);
        const unsigned prev = __hip_atomic_fetch_add(done, 1u, __ATOMIC_ACQ_REL,
                                                     __HIP_MEMORY_SCOPE_AGENT);
        amlast = (prev == (unsigned)(K2TOT - 1)) ? 1 : 0;
    }
    __syncthreads();
    if (!amlast) return;

    // ---- finisher: obj partial reduce + final scalar
    float so = 0.0f;
    for (int k = tid; k < B_ * K1BLK; k += 256) so += pobj[k];
    __shared__ float red[256];
    red[tid] = so;
    __syncthreads();
    for (int s = 128; s > 0; s >>= 1) {
        if (tid < s) red[tid] += red[tid + s];
        __syncthreads();
    }
    if (tid == 0) {
        const float posumT = __hip_atomic_load(&acc[0], __ATOMIC_RELAXED, __HIP_MEMORY_SCOPE_AGENT);
        const float boxT   = __hip_atomic_load(&acc[1], __ATOMIC_RELAXED, __HIP_MEMORY_SCOPE_AGENT);
        const float clsT   = __hip_atomic_load(&acc[2], __ATOMIC_RELAXED, __HIP_MEMORY_SCOPE_AGENT);
        const float nposT  = __hip_atomic_load(&acc[3], __ATOMIC_RELAXED, __HIP_MEMORY_SCOPE_AGENT);
        const float n_pos = fmaxf(nposT, 1.0f);
        out[0] = 7.5f * boxT / n_pos
               + 0.5f * clsT / n_pos
               + (red[0] - posumT) / (float)N_;
    }
}

extern "C" void kernel_launch(void* const* d_in, const int* in_sizes, int n_in,
                              void* d_out, int out_size, void* d_ws, size_t ws_size,
                              hipStream_t stream)
{
    const float* pred = (const float*)d_in[0];
    const float* gtb  = (const float*)d_in[1];
    const int*   gtc  = (const int*)d_in[2];
    const float* anc  = (const float*)d_in[3];

    char* ws = (char*)d_ws;
    size_t off = 0;
    auto take = [&](size_t bytes) {
        size_t o = off;
        off += (bytes + 255) & ~(size_t)255;
        return o;
    };
    int*                cidx_pad = (int*)(ws + take((size_t)B_ * PADW * 4));
    unsigned long long* bkey     = (unsigned long long*)(ws + take((size_t)B_ * N_ * 8));
    float*              spsum    = (float*)(ws + take((size_t)B_ * N_ * 4));
    float*              pobj     = (float*)(ws + take((size_t)B_ * K1BLK * 4));
    int*                bcount   = (int*)(ws + take((size_t)B_ * K1BLK * 4));
    float*              acc      = (float*)(ws + take(4 * 4));
    unsigned int*       done     = (unsigned int*)(ws + take(4));

    dim3 g1(K1BLK, B_);
    k1_prep<<<g1, 256, 0, stream>>>(gtb, anc, pred, cidx_pad, spsum, bkey,
                                    pobj, bcount, acc, done);
    dim3 g2(G_, B_);
    k2_assign<<<g2, 256, 0, stream>>>(pred, gtb, gtc, cidx_pad, bcount, spsum,
                                      bkey, pobj, acc, done, (float*)d_out);
}